// Round 4
// baseline (298.699 us; speedup 1.0000x reference)
//
#include <hip/hip_runtime.h>
#include <math.h>

// Problem shapes (fixed by setup_inputs)
#define B 64
#define T 512
#define D 768
#define D4 192         // D / 4
#define V 20
#define NEG -1000000000.0f
#define TCH 64         // tokens per chunk (one block per chunk)
#define NCH 8          // T / TCH
#define NBLK 512       // B * NCH
#define NTHR 256

// ---------------------------------------------------------------------------
// Software grid barrier: device-scope atomic counter per sync point, zeroed
// by hipMemsetAsync before each launch. Co-residency of all NBLK blocks is
// structural: __launch_bounds__(256,2) caps VGPR<=256 -> >=2 blocks/CU ->
// 512 resident on 256 CUs.
// ---------------------------------------------------------------------------
__device__ __forceinline__ void grid_barrier(unsigned* cnt) {
  __syncthreads();
  if (threadIdx.x == 0) {
    __threadfence();               // release: prior writes visible device-wide
    atomicAdd(cnt, 1u);
    while (atomicAdd(cnt, 0u) < (unsigned)NBLK) __builtin_amdgcn_s_sleep(1);
    __threadfence();               // acquire: other blocks' writes visible
  }
  __syncthreads();
}

// ---------------------------------------------------------------------------
// One kernel, 4 phases:
//  A: per-chunk masked sum (compacted token list, 2-wide unrolled float4
//     loads) -> V=20 partial value-score dots -> ws.pd
//  B: (blocks<64) value softmax + value_embedding -> d_out
//  C: per-chunk fused pooling: dot(emb,vemb) + 2-token online softmax,
//     emb fragments reused in registers -> ws.{scores,pm,pl,pacc}
//  D: (blocks<64) combine chunks -> pooled_embedding + pooling_probs
// ---------------------------------------------------------------------------
__global__ __launch_bounds__(NTHR, 2) void k_fused_all(
    const float4* __restrict__ emb4, const int* __restrict__ emask,
    const int* __restrict__ vmask, const float* __restrict__ W,
    float* __restrict__ vemb_out, float* __restrict__ pooled_out,
    float* __restrict__ vprobs_out, float* __restrict__ pprobs_out,
    float* __restrict__ ws, unsigned* __restrict__ bar) {
  const int bc = blockIdx.x;
  const int b = bc >> 3;  // / NCH
  const int c = bc & 7;   // % NCH
  const int tid = threadIdx.x;
  const int wave = tid >> 6, lane = tid & 63;

  // ws layout (floats)
  float* pacc = ws;                  // NBLK*D
  float* scores = pacc + NBLK * D;   // B*T
  float* pm = scores + B * T;        // NBLK
  float* pl = pm + NBLK;             // NBLK
  float* pd = pl + NBLK;             // NBLK*V

  __shared__ float4 lacc4[4][D4];    // 12 KB
  __shared__ float msum[D];          // 3 KB
  __shared__ int idx[TCH];
  __shared__ int scnt;
  __shared__ float lm[4], ll[4], coS[NCH];
  __shared__ float sc[V], pr[V];
  __shared__ float sM, sinvL;

  // ---- compact unmasked token list for this chunk ----
  if (tid == 0) {
    int n = 0;
    const int* em = emask + b * T + c * TCH;
    for (int t = 0; t < TCH; ++t)
      if (em[t]) idx[n++] = t;
    scnt = n;
  }
  __syncthreads();
  const int cnt = scnt;
  const float4* eb = emb4 + ((size_t)b * T + (size_t)c * TCH) * D4;

  // ================= Phase A: masked chunk sum + partial V-dots ============
  {
    float4 s0 = {0.f, 0.f, 0.f, 0.f}, s1 = s0, s2 = s0;
    int i = wave;
    for (; i + 4 < cnt; i += 8) {
      const float4* ea = eb + (size_t)idx[i] * D4 + lane;
      const float4* ec = eb + (size_t)idx[i + 4] * D4 + lane;
      float4 a0 = ea[0], a1 = ea[64], a2 = ea[128];
      float4 b0 = ec[0], b1 = ec[64], b2 = ec[128];
      s0.x += a0.x + b0.x; s0.y += a0.y + b0.y;
      s0.z += a0.z + b0.z; s0.w += a0.w + b0.w;
      s1.x += a1.x + b1.x; s1.y += a1.y + b1.y;
      s1.z += a1.z + b1.z; s1.w += a1.w + b1.w;
      s2.x += a2.x + b2.x; s2.y += a2.y + b2.y;
      s2.z += a2.z + b2.z; s2.w += a2.w + b2.w;
    }
    if (i < cnt) {
      const float4* ea = eb + (size_t)idx[i] * D4 + lane;
      float4 a0 = ea[0], a1 = ea[64], a2 = ea[128];
      s0.x += a0.x; s0.y += a0.y; s0.z += a0.z; s0.w += a0.w;
      s1.x += a1.x; s1.y += a1.y; s1.z += a1.z; s1.w += a1.w;
      s2.x += a2.x; s2.y += a2.y; s2.z += a2.z; s2.w += a2.w;
    }
    lacc4[wave][lane] = s0;
    lacc4[wave][lane + 64] = s1;
    lacc4[wave][lane + 128] = s2;
    __syncthreads();
    if (tid < D4) {
      float4 a = lacc4[0][tid], x = lacc4[1][tid], y = lacc4[2][tid],
             z = lacc4[3][tid];
      float4 r;
      r.x = a.x + x.x + y.x + z.x;
      r.y = a.y + x.y + y.y + z.y;
      r.z = a.z + x.z + y.z + z.z;
      r.w = a.w + x.w + y.w + z.w;
      *(float4*)&msum[4 * tid] = r;
    }
    __syncthreads();
    for (int v = wave; v < V; v += 4) {
      float p = 0.f;
      const float* wv = W + (size_t)v * D;
      for (int j = 0; j < 12; ++j) {
        int d = lane + 64 * j;
        p += msum[d] * wv[d];
      }
      for (int off = 32; off; off >>= 1) p += __shfl_xor(p, off, 64);
      if (lane == 0) pd[bc * V + v] = p;
    }
  }
  grid_barrier(bar + 0);

  // ================= Phase B: value softmax + value_embedding ==============
  if (bc < B) {
    if (tid < V) {
      float s = 0.f;
      for (int cc = 0; cc < NCH; ++cc) s += pd[(bc * NCH + cc) * V + tid];
      sc[tid] = s + (vmask[bc * V + tid] ? 0.f : NEG);
    }
    __syncthreads();
    if (tid == 0) {
      float m = sc[0];
      for (int v = 1; v < V; ++v) m = fmaxf(m, sc[v]);
      float ssum = 0.f;
      for (int v = 0; v < V; ++v) {
        float e = expf(sc[v] - m);
        pr[v] = e;
        ssum += e;
      }
      float inv = 1.f / ssum;
      for (int v = 0; v < V; ++v) {
        pr[v] *= inv;
        vprobs_out[bc * V + v] = pr[v];
      }
    }
    __syncthreads();
    if (tid < D4) {
      float4 a = {0.f, 0.f, 0.f, 0.f};
      for (int v = 0; v < V; ++v) {
        float p = pr[v];
        float4 w4 = *(const float4*)&W[(size_t)v * D + 4 * tid];
        a.x += p * w4.x; a.y += p * w4.y;
        a.z += p * w4.z; a.w += p * w4.w;
      }
      ((float4*)vemb_out)[(size_t)bc * D4 + tid] = a;
    }
  }
  grid_barrier(bar + 1);

  // ================= Phase C: fused pooling pass over chunk ================
  {
    const float4* vb = (const float4*)vemb_out + (size_t)b * D4;
    float4 ve0 = vb[lane], ve1 = vb[lane + 64], ve2 = vb[lane + 128];
    float* srow = scores + b * T + c * TCH;
    float m = NEG, l = 0.f;
    float4 a0 = {0.f, 0.f, 0.f, 0.f}, a1 = a0, a2 = a0;
    int i = wave;
    for (; i + 4 < cnt; i += 8) {
      int t0 = idx[i], t1 = idx[i + 4];
      const float4* ea = eb + (size_t)t0 * D4 + lane;
      const float4* ec = eb + (size_t)t1 * D4 + lane;
      float4 e0 = ea[0], e1 = ea[64], e2 = ea[128];
      float4 f0 = ec[0], f1 = ec[64], f2 = ec[128];
      float p0 = e0.x * ve0.x + e0.y * ve0.y + e0.z * ve0.z + e0.w * ve0.w +
                 e1.x * ve1.x + e1.y * ve1.y + e1.z * ve1.z + e1.w * ve1.w +
                 e2.x * ve2.x + e2.y * ve2.y + e2.z * ve2.z + e2.w * ve2.w;
      float p1 = f0.x * ve0.x + f0.y * ve0.y + f0.z * ve0.z + f0.w * ve0.w +
                 f1.x * ve1.x + f1.y * ve1.y + f1.z * ve1.z + f1.w * ve1.w +
                 f2.x * ve2.x + f2.y * ve2.y + f2.z * ve2.z + f2.w * ve2.w;
      for (int off = 32; off; off >>= 1) {
        p0 += __shfl_xor(p0, off, 64);
        p1 += __shfl_xor(p1, off, 64);
      }
      if (lane == 0) { srow[t0] = p0; srow[t1] = p1; }
      float mn = fmaxf(m, fmaxf(p0, p1));
      float scale = expf(m - mn);  // ==0 on first iteration (m=NEG)
      float w0 = expf(p0 - mn), w1 = expf(p1 - mn);
      l = l * scale + w0 + w1;
      a0.x = a0.x * scale + w0 * e0.x + w1 * f0.x;
      a0.y = a0.y * scale + w0 * e0.y + w1 * f0.y;
      a0.z = a0.z * scale + w0 * e0.z + w1 * f0.z;
      a0.w = a0.w * scale + w0 * e0.w + w1 * f0.w;
      a1.x = a1.x * scale + w0 * e1.x + w1 * f1.x;
      a1.y = a1.y * scale + w0 * e1.y + w1 * f1.y;
      a1.z = a1.z * scale + w0 * e1.z + w1 * f1.z;
      a1.w = a1.w * scale + w0 * e1.w + w1 * f1.w;
      a2.x = a2.x * scale + w0 * e2.x + w1 * f2.x;
      a2.y = a2.y * scale + w0 * e2.y + w1 * f2.y;
      a2.z = a2.z * scale + w0 * e2.z + w1 * f2.z;
      a2.w = a2.w * scale + w0 * e2.w + w1 * f2.w;
      m = mn;
    }
    if (i < cnt) {
      int t0 = idx[i];
      const float4* ea = eb + (size_t)t0 * D4 + lane;
      float4 e0 = ea[0], e1 = ea[64], e2 = ea[128];
      float p0 = e0.x * ve0.x + e0.y * ve0.y + e0.z * ve0.z + e0.w * ve0.w +
                 e1.x * ve1.x + e1.y * ve1.y + e1.z * ve1.z + e1.w * ve1.w +
                 e2.x * ve2.x + e2.y * ve2.y + e2.z * ve2.z + e2.w * ve2.w;
      for (int off = 32; off; off >>= 1) p0 += __shfl_xor(p0, off, 64);
      if (lane == 0) srow[t0] = p0;
      float mn = fmaxf(m, p0);
      float scale = expf(m - mn);
      float w0 = expf(p0 - mn);
      l = l * scale + w0;
      a0.x = a0.x * scale + w0 * e0.x; a0.y = a0.y * scale + w0 * e0.y;
      a0.z = a0.z * scale + w0 * e0.z; a0.w = a0.w * scale + w0 * e0.w;
      a1.x = a1.x * scale + w0 * e1.x; a1.y = a1.y * scale + w0 * e1.y;
      a1.z = a1.z * scale + w0 * e1.z; a1.w = a1.w * scale + w0 * e1.w;
      a2.x = a2.x * scale + w0 * e2.x; a2.y = a2.y * scale + w0 * e2.y;
      a2.z = a2.z * scale + w0 * e2.z; a2.w = a2.w * scale + w0 * e2.w;
      m = mn;
    }
    if (lane == 0) { lm[wave] = m; ll[wave] = l; }
    lacc4[wave][lane] = a0;
    lacc4[wave][lane + 64] = a1;
    lacc4[wave][lane + 128] = a2;
    __syncthreads();
    if (tid == 0) {
      float M = fmaxf(fmaxf(lm[0], lm[1]), fmaxf(lm[2], lm[3]));
      float L = 0.f;
      for (int w2 = 0; w2 < 4; ++w2) {
        float cw = expf(lm[w2] - M);
        coS[w2] = cw;
        L += ll[w2] * cw;
      }
      pm[bc] = M;
      pl[bc] = L;
    }
    __syncthreads();
    if (tid < D4) {
      float4 r = {0.f, 0.f, 0.f, 0.f};
      for (int w2 = 0; w2 < 4; ++w2) {
        float cw = coS[w2];
        float4 a = lacc4[w2][tid];
        r.x += cw * a.x; r.y += cw * a.y;
        r.z += cw * a.z; r.w += cw * a.w;
      }
      ((float4*)pacc)[(size_t)bc * D4 + tid] = r;
    }
  }
  grid_barrier(bar + 2);

  // ================= Phase D: pooled embedding + probs =====================
  if (bc < B) {
    if (tid == 0) {
      float M = NEG;
      for (int cc = 0; cc < NCH; ++cc) M = fmaxf(M, pm[bc * NCH + cc]);
      float L = 0.f;
      for (int cc = 0; cc < NCH; ++cc)
        L += pl[bc * NCH + cc] * expf(pm[bc * NCH + cc] - M);
      float invL = 1.f / L;
      for (int cc = 0; cc < NCH; ++cc)
        coS[cc] = expf(pm[bc * NCH + cc] - M) * invL;
      sM = M;
      sinvL = invL;
    }
    __syncthreads();
    if (tid < D4) {
      float4 r = {0.f, 0.f, 0.f, 0.f};
      for (int cc = 0; cc < NCH; ++cc) {
        float cw = coS[cc];
        float4 a = ((const float4*)pacc)[(size_t)(bc * NCH + cc) * D4 + tid];
        r.x += cw * a.x; r.y += cw * a.y;
        r.z += cw * a.z; r.w += cw * a.w;
      }
      ((float4*)pooled_out)[(size_t)bc * D4 + tid] = r;
    }
    float M = sM, invL = sinvL;
    for (int k = 0; k < 2; ++k) {
      int t = tid + 256 * k;
      pprobs_out[bc * T + t] =
          emask[bc * T + t] ? expf(scores[bc * T + t] - M) * invL : 0.f;
    }
  }
}

extern "C" void kernel_launch(void* const* d_in, const int* in_sizes, int n_in,
                              void* d_out, int out_size, void* d_ws,
                              size_t ws_size, hipStream_t stream) {
  const float4* emb4 = (const float4*)d_in[0];  // (B,T,D)
  const int* emask = (const int*)d_in[1];       // (B,T)
  const int* vmask = (const int*)d_in[2];       // (B,V)
  const float* W = (const float*)d_in[3];       // (V,D)

  float* out = (float*)d_out;
  float* vemb_out = out;                        // B*D
  float* pooled_out = out + B * D;              // B*D
  float* vprobs_out = out + 2 * B * D;          // B*V
  float* pprobs_out = out + 2 * B * D + B * V;  // B*T

  float* ws = (float*)d_ws;
  // floats used: NBLK*D + B*T + NBLK + NBLK + NBLK*V
  size_t ws_floats = (size_t)NBLK * D + B * T + 2 * NBLK + NBLK * V;
  unsigned* bar = (unsigned*)(ws + ws_floats);

  hipMemsetAsync(bar, 0, 64, stream);  // zero the 3 barrier counters
  k_fused_all<<<dim3(NBLK), dim3(NTHR), 0, stream>>>(
      emb4, emask, vmask, W, vemb_out, pooled_out, vprobs_out, pprobs_out, ws,
      bar);
}

// Round 5
// 165.557 us; speedup vs baseline: 1.8042x; 1.8042x over previous
//
#include <hip/hip_runtime.h>
#include <math.h>

// Problem shapes (fixed by setup_inputs)
#define B 64
#define T 512
#define D 768
#define D4 192          // D / 4
#define V 20
#define NEG -1000000000.0f
#define TCH 32          // tokens per chunk
#define NCH 16          // T / TCH
#define NBLK (B * NCH)  // 1024 blocks for the big kernels

// ---------------------------------------------------------------------------
// K1: per-chunk masked sum (compacted token list, 2-wide unrolled float4
// streaming) + V=20 partial value-score dots -> pd[B*NCH*V].
// grid = 1024 x 256 (4 waves). The only HBM-cold pass over emb (~51 MB).
// ---------------------------------------------------------------------------
__global__ __launch_bounds__(256) void k_sum_vdots(
    const float4* __restrict__ emb4, const int* __restrict__ emask,
    const float* __restrict__ W, float* __restrict__ pd) {
  const int bc = blockIdx.x, b = bc >> 4, c = bc & 15;
  const int tid = threadIdx.x, wave = tid >> 6, lane = tid & 63;
  __shared__ int sm[TCH];
  __shared__ int idx[TCH];
  __shared__ int scnt;
  __shared__ float4 lacc4[4][D4];  // 12 KB
  __shared__ float msum[D];        // 3 KB

  if (tid < TCH) sm[tid] = emask[b * T + c * TCH + tid];
  __syncthreads();
  if (tid == 0) {  // compact from LDS (cheap), not from global
    int n = 0;
    for (int t = 0; t < TCH; ++t)
      if (sm[t]) idx[n++] = t;
    scnt = n;
  }
  __syncthreads();
  const int cnt = scnt;
  const float4* eb = emb4 + ((size_t)b * T + (size_t)c * TCH) * D4;

  float4 s0 = {0.f, 0.f, 0.f, 0.f}, s1 = s0, s2 = s0;
  int i = wave;
  for (; i + 4 < cnt; i += 8) {  // 2 tokens, 6 loads in flight
    const float4* ea = eb + (size_t)idx[i] * D4 + lane;
    const float4* ec = eb + (size_t)idx[i + 4] * D4 + lane;
    float4 a0 = ea[0], a1 = ea[64], a2 = ea[128];
    float4 b0 = ec[0], b1 = ec[64], b2 = ec[128];
    s0.x += a0.x + b0.x; s0.y += a0.y + b0.y;
    s0.z += a0.z + b0.z; s0.w += a0.w + b0.w;
    s1.x += a1.x + b1.x; s1.y += a1.y + b1.y;
    s1.z += a1.z + b1.z; s1.w += a1.w + b1.w;
    s2.x += a2.x + b2.x; s2.y += a2.y + b2.y;
    s2.z += a2.z + b2.z; s2.w += a2.w + b2.w;
  }
  if (i < cnt) {
    const float4* ea = eb + (size_t)idx[i] * D4 + lane;
    float4 a0 = ea[0], a1 = ea[64], a2 = ea[128];
    s0.x += a0.x; s0.y += a0.y; s0.z += a0.z; s0.w += a0.w;
    s1.x += a1.x; s1.y += a1.y; s1.z += a1.z; s1.w += a1.w;
    s2.x += a2.x; s2.y += a2.y; s2.z += a2.z; s2.w += a2.w;
  }
  lacc4[wave][lane] = s0;
  lacc4[wave][lane + 64] = s1;
  lacc4[wave][lane + 128] = s2;
  __syncthreads();
  if (tid < D4) {
    float4 a = lacc4[0][tid], x = lacc4[1][tid], y = lacc4[2][tid],
           z = lacc4[3][tid];
    float4 r;
    r.x = a.x + x.x + y.x + z.x;
    r.y = a.y + x.y + y.y + z.y;
    r.z = a.z + x.z + y.z + z.z;
    r.w = a.w + x.w + y.w + z.w;
    *(float4*)&msum[4 * tid] = r;
  }
  __syncthreads();
  for (int v = wave; v < V; v += 4) {
    float p = 0.f;
    const float* wv = W + (size_t)v * D;
    for (int j = 0; j < 12; ++j) {
      int d = lane + 64 * j;
      p += msum[d] * wv[d];
    }
    for (int off = 32; off; off >>= 1) p += __shfl_xor(p, off, 64);
    if (lane == 0) pd[bc * V + v] = p;
  }
}

// ---------------------------------------------------------------------------
// K2: fused. Every block REDUNDANTLY recomputes its batch's value softmax +
// value_embedding (tiny: 320-float pd read, 20 exps, 15K FMAs vs L2-hot W),
// then runs the pooling pass over its chunk with online softmax, reusing the
// emb fragments already in registers. c==0 blocks also write vprobs/vemb out.
// grid = 1024 x 256. emb re-read is L3-warm.
// ---------------------------------------------------------------------------
__global__ __launch_bounds__(256) void k_fused_pool(
    const float4* __restrict__ emb4, const int* __restrict__ emask,
    const int* __restrict__ vmask, const float* __restrict__ W,
    const float* __restrict__ pd, float* __restrict__ vemb_out,
    float* __restrict__ vprobs_out, float* __restrict__ scores,
    float* __restrict__ pm, float* __restrict__ pl,
    float4* __restrict__ pacc4) {
  const int bc = blockIdx.x, b = bc >> 4, c = bc & 15;
  const int tid = threadIdx.x, wave = tid >> 6, lane = tid & 63;
  __shared__ int sm[TCH];
  __shared__ int idx[TCH];
  __shared__ int scnt;
  __shared__ float4 lacc4[4][D4];  // 12 KB
  __shared__ float vemb[D];        // 3 KB
  __shared__ float sc[V], pr[V];
  __shared__ float lm[4], ll[4], co4[4];

  if (tid < TCH) sm[tid] = emask[b * T + c * TCH + tid];
  __syncthreads();
  if (tid == 0) {
    int n = 0;
    for (int t = 0; t < TCH; ++t)
      if (sm[t]) idx[n++] = t;
    scnt = n;
  }

  // ---- redundant per-block value softmax ----
  if (tid < V) {
    float s = 0.f;
    for (int cc = 0; cc < NCH; ++cc) s += pd[(b * NCH + cc) * V + tid];
    sc[tid] = s + (vmask[b * V + tid] ? 0.f : NEG);
  }
  __syncthreads();
  if (tid == 0) {
    float m = sc[0];
    for (int v = 1; v < V; ++v) m = fmaxf(m, sc[v]);
    float ssum = 0.f;
    for (int v = 0; v < V; ++v) {
      float e = expf(sc[v] - m);
      pr[v] = e;
      ssum += e;
    }
    float inv = 1.f / ssum;
    for (int v = 0; v < V; ++v) {
      pr[v] *= inv;
      if (c == 0) vprobs_out[b * V + v] = pr[v];
    }
  }
  __syncthreads();
  // vemb[d] = sum_v pr[v] * W[v,d]  (coalesced W reads, L2-hot)
  for (int k = 0; k < 3; ++k) {
    int d = tid + 256 * k;
    float a = 0.f;
    for (int v = 0; v < V; ++v) a += pr[v] * W[(size_t)v * D + d];
    vemb[d] = a;
    if (c == 0) vemb_out[(size_t)b * D + d] = a;
  }
  __syncthreads();

  // ---- pooling pass over this chunk (online softmax, 2-wide unroll) ----
  const int cnt = scnt;
  const float4* eb = emb4 + ((size_t)b * T + (size_t)c * TCH) * D4;
  const float4* vb = (const float4*)vemb;
  float4 ve0 = vb[lane], ve1 = vb[lane + 64], ve2 = vb[lane + 128];
  float* srow = scores + b * T + c * TCH;
  float m = NEG, l = 0.f;
  float4 a0 = {0.f, 0.f, 0.f, 0.f}, a1 = a0, a2 = a0;
  int i = wave;
  for (; i + 4 < cnt; i += 8) {
    int t0 = idx[i], t1 = idx[i + 4];
    const float4* ea = eb + (size_t)t0 * D4 + lane;
    const float4* ec = eb + (size_t)t1 * D4 + lane;
    float4 e0 = ea[0], e1 = ea[64], e2 = ea[128];
    float4 f0 = ec[0], f1 = ec[64], f2 = ec[128];
    float p0 = e0.x * ve0.x + e0.y * ve0.y + e0.z * ve0.z + e0.w * ve0.w +
               e1.x * ve1.x + e1.y * ve1.y + e1.z * ve1.z + e1.w * ve1.w +
               e2.x * ve2.x + e2.y * ve2.y + e2.z * ve2.z + e2.w * ve2.w;
    float p1 = f0.x * ve0.x + f0.y * ve0.y + f0.z * ve0.z + f0.w * ve0.w +
               f1.x * ve1.x + f1.y * ve1.y + f1.z * ve1.z + f1.w * ve1.w +
               f2.x * ve2.x + f2.y * ve2.y + f2.z * ve2.z + f2.w * ve2.w;
    for (int off = 32; off; off >>= 1) {
      p0 += __shfl_xor(p0, off, 64);
      p1 += __shfl_xor(p1, off, 64);
    }
    if (lane == 0) { srow[t0] = p0; srow[t1] = p1; }
    float mn = fmaxf(m, fmaxf(p0, p1));
    float scale = expf(m - mn);  // 0 on first iteration (m = NEG)
    float w0 = expf(p0 - mn), w1 = expf(p1 - mn);
    l = l * scale + w0 + w1;
    a0.x = a0.x * scale + w0 * e0.x + w1 * f0.x;
    a0.y = a0.y * scale + w0 * e0.y + w1 * f0.y;
    a0.z = a0.z * scale + w0 * e0.z + w1 * f0.z;
    a0.w = a0.w * scale + w0 * e0.w + w1 * f0.w;
    a1.x = a1.x * scale + w0 * e1.x + w1 * f1.x;
    a1.y = a1.y * scale + w0 * e1.y + w1 * f1.y;
    a1.z = a1.z * scale + w0 * e1.z + w1 * f1.z;
    a1.w = a1.w * scale + w0 * e1.w + w1 * f1.w;
    a2.x = a2.x * scale + w0 * e2.x + w1 * f2.x;
    a2.y = a2.y * scale + w0 * e2.y + w1 * f2.y;
    a2.z = a2.z * scale + w0 * e2.z + w1 * f2.z;
    a2.w = a2.w * scale + w0 * e2.w + w1 * f2.w;
    m = mn;
  }
  if (i < cnt) {
    int t0 = idx[i];
    const float4* ea = eb + (size_t)t0 * D4 + lane;
    float4 e0 = ea[0], e1 = ea[64], e2 = ea[128];
    float p0 = e0.x * ve0.x + e0.y * ve0.y + e0.z * ve0.z + e0.w * ve0.w +
               e1.x * ve1.x + e1.y * ve1.y + e1.z * ve1.z + e1.w * ve1.w +
               e2.x * ve2.x + e2.y * ve2.y + e2.z * ve2.z + e2.w * ve2.w;
    for (int off = 32; off; off >>= 1) p0 += __shfl_xor(p0, off, 64);
    if (lane == 0) srow[t0] = p0;
    float mn = fmaxf(m, p0);
    float scale = expf(m - mn);
    float w0 = expf(p0 - mn);
    l = l * scale + w0;
    a0.x = a0.x * scale + w0 * e0.x; a0.y = a0.y * scale + w0 * e0.y;
    a0.z = a0.z * scale + w0 * e0.z; a0.w = a0.w * scale + w0 * e0.w;
    a1.x = a1.x * scale + w0 * e1.x; a1.y = a1.y * scale + w0 * e1.y;
    a1.z = a1.z * scale + w0 * e1.z; a1.w = a1.w * scale + w0 * e1.w;
    a2.x = a2.x * scale + w0 * e2.x; a2.y = a2.y * scale + w0 * e2.y;
    a2.z = a2.z * scale + w0 * e2.z; a2.w = a2.w * scale + w0 * e2.w;
    m = mn;
  }
  if (lane == 0) { lm[wave] = m; ll[wave] = l; }
  lacc4[wave][lane] = a0;
  lacc4[wave][lane + 64] = a1;
  lacc4[wave][lane + 128] = a2;
  __syncthreads();
  if (tid == 0) {
    float M = fmaxf(fmaxf(lm[0], lm[1]), fmaxf(lm[2], lm[3]));
    float L = 0.f;
    for (int w2 = 0; w2 < 4; ++w2) {
      float cw = expf(lm[w2] - M);
      co4[w2] = cw;
      L += ll[w2] * cw;
    }
    pm[bc] = M;
    pl[bc] = L;
  }
  __syncthreads();
  if (tid < D4) {
    float4 r = {0.f, 0.f, 0.f, 0.f};
    for (int w2 = 0; w2 < 4; ++w2) {
      float cw = co4[w2];
      float4 a = lacc4[w2][tid];
      r.x += cw * a.x; r.y += cw * a.y;
      r.z += cw * a.z; r.w += cw * a.w;
    }
    pacc4[(size_t)bc * D4 + tid] = r;
  }
}

// ---------------------------------------------------------------------------
// K3: per-batch finalize — combine chunk (m,l,acc) -> pooled_embedding +
// pooling_probs. grid = 64 x 256. Tiny.
// ---------------------------------------------------------------------------
__global__ __launch_bounds__(256) void k_finalize(
    const float* __restrict__ pm, const float* __restrict__ pl,
    const float4* __restrict__ pacc4, const float* __restrict__ scores,
    const int* __restrict__ emask, float* __restrict__ pooled,
    float* __restrict__ pprobs) {
  const int b = blockIdx.x, tid = threadIdx.x;
  __shared__ float co[NCH];
  __shared__ float sM, sinvL;
  if (tid == 0) {
    float M = NEG;
    for (int cc = 0; cc < NCH; ++cc) M = fmaxf(M, pm[b * NCH + cc]);
    float L = 0.f;
    for (int cc = 0; cc < NCH; ++cc)
      L += pl[b * NCH + cc] * expf(pm[b * NCH + cc] - M);
    float invL = 1.f / L;
    for (int cc = 0; cc < NCH; ++cc)
      co[cc] = expf(pm[b * NCH + cc] - M) * invL;
    sM = M;
    sinvL = invL;
  }
  __syncthreads();
  if (tid < D4) {
    float4 r = {0.f, 0.f, 0.f, 0.f};
    for (int cc = 0; cc < NCH; ++cc) {
      float cw = co[cc];
      float4 a = pacc4[(size_t)(b * NCH + cc) * D4 + tid];
      r.x += cw * a.x; r.y += cw * a.y;
      r.z += cw * a.z; r.w += cw * a.w;
    }
    ((float4*)pooled)[(size_t)b * D4 + tid] = r;
  }
  float M = sM, invL = sinvL;
  for (int k = 0; k < 2; ++k) {
    int t = tid + 256 * k;
    pprobs[b * T + t] =
        emask[b * T + t] ? expf(scores[b * T + t] - M) * invL : 0.f;
  }
}

extern "C" void kernel_launch(void* const* d_in, const int* in_sizes, int n_in,
                              void* d_out, int out_size, void* d_ws,
                              size_t ws_size, hipStream_t stream) {
  const float4* emb4 = (const float4*)d_in[0];  // (B,T,D)
  const int* emask = (const int*)d_in[1];       // (B,T)
  const int* vmask = (const int*)d_in[2];       // (B,V)
  const float* W = (const float*)d_in[3];       // (V,D)

  float* out = (float*)d_out;
  float* vemb_out = out;                        // B*D
  float* pooled_out = out + B * D;              // B*D
  float* vprobs_out = out + 2 * B * D;          // B*V
  float* pprobs_out = out + 2 * B * D + B * V;  // B*T

  float* ws = (float*)d_ws;
  float* pacc = ws;                  // NBLK*D
  float* scores = pacc + NBLK * D;   // B*T
  float* pm = scores + B * T;        // NBLK
  float* pl = pm + NBLK;             // NBLK
  float* pd = pl + NBLK;             // NBLK*V

  k_sum_vdots<<<dim3(NBLK), dim3(256), 0, stream>>>(emb4, emask, W, pd);
  k_fused_pool<<<dim3(NBLK), dim3(256), 0, stream>>>(
      emb4, emask, vmask, W, pd, vemb_out, vprobs_out, scores, pm, pl,
      (float4*)pacc);
  k_finalize<<<dim3(B), dim3(256), 0, stream>>>(pm, pl, (const float4*)pacc,
                                                scores, emask, pooled_out,
                                                pprobs_out);
}